// Round 12
// baseline (564.609 us; speedup 1.0000x reference)
//
#include <hip/hip_runtime.h>
#include <hip/hip_bf16.h>

#define NN 100000
#define EE 640000
#define NB_SCAN 98   // ceil(NN/1024)
#define G_E3 2048    // k_edge3 blocks (8192 waves; 40000 tile-pairs)

typedef short bf16x8 __attribute__((ext_vector_type(8)));
typedef float f32x4 __attribute__((ext_vector_type(4)));

__device__ __forceinline__ ushort f2bf(float f){
  uint u = __float_as_uint(f);
  u += 0x7fffu + ((u >> 16) & 1u);   // round-to-nearest-even
  return (ushort)(u >> 16);
}
__device__ __forceinline__ float bf2f(ushort s){ return __uint_as_float(((uint)s) << 16); }
__device__ __forceinline__ uint pack2(float a, float b){ return ((uint)f2bf(b) << 16) | (uint)f2bf(a); }
__device__ __forceinline__ uint swz(uint row, uint colB, uint strideB){
  return row * strideB + (colB ^ ((row & 7u) << 4));
}

// ---------------- K0: weight prep (fp32 -> bf16, transposed [col][k]) + zero deg -----
__global__ void k_prep(const float* __restrict__ Wq, const float* __restrict__ Wk,
                       const float* __restrict__ Wv, const float* __restrict__ Wsk,
                       const float* __restrict__ We,
                       ushort* __restrict__ W4t, ushort* __restrict__ Wet,
                       int* __restrict__ deg){
  int tid = blockIdx.x * 256 + threadIdx.x;
  if (tid < 512 * 128){              // W4t[col 0..511][k 0..127], cols: q|k|v|skip
    int col = tid >> 7, k = tid & 127;
    const float* W = (col < 128) ? Wq : ((col < 256) ? Wk : ((col < 384) ? Wv : Wsk));
    W4t[tid] = f2bf(W[k * 128 + (col & 127)]);
  }
  if (tid < 128 * 256){              // Wet[col 0..127][k 0..255]
    int col = tid >> 8, k = tid & 255;
    Wet[tid] = f2bf(We[k * 128 + col]);
  }
  if (tid < NN) deg[tid] = 0;
}

// ---------------- K1: node GEMM x@[Wq|Wk|Wv|Wskip], 64-row tiles, bf16 MFMA ----------
__global__ __launch_bounds__(256) void k_node(
    const float* __restrict__ x, const ushort* __restrict__ W4t,
    const float* __restrict__ bq, const float* __restrict__ bk,
    const float* __restrict__ bv, const float* __restrict__ bsk,
    ushort* __restrict__ q_n, ushort* __restrict__ kv,
    float* __restrict__ out){
  __shared__ ushort As[64 * 128];
  __shared__ ushort Bs[128 * 128];
  char* Ab = (char*)As; char* Bb = (char*)Bs;
  int tid = threadIdx.x;
  int n0 = blockIdx.x * 64;
  {
    int row = tid >> 2, part = tid & 3;
    int gr = n0 + row;
    for (int j = 0; j < 4; j++){
      float4 a = make_float4(0.f,0.f,0.f,0.f), b = a;
      if (gr < NN){
        const float4* p = (const float4*)(x + (size_t)gr * 128 + part * 32 + j * 8);
        a = p[0]; b = p[1];
      }
      uint4 w; w.x = pack2(a.x,a.y); w.y = pack2(a.z,a.w); w.z = pack2(b.x,b.y); w.w = pack2(b.z,b.w);
      *(uint4*)(Ab + swz(row, (uint)(part * 64 + j * 16), 256)) = w;
    }
  }
  int wid = tid >> 6, l = tid & 63, lr = l & 15, lg = l >> 4;
  for (int chunk = 0; chunk < 4; ++chunk){
    if (chunk) __syncthreads();
    {
      int row = tid >> 1, half = tid & 1;
      const ushort* src = W4t + (size_t)(chunk * 128 + row) * 128 + half * 64;
      for (int j = 0; j < 8; j++){
        uint4 w = *(const uint4*)(src + j * 8);
        *(uint4*)(Bb + swz(row, (uint)(half * 128 + j * 16), 256)) = w;
      }
    }
    __syncthreads();
    f32x4 acc[8];
    for (int i = 0; i < 8; i++) acc[i] = (f32x4){0.f,0.f,0.f,0.f};
    for (int ks = 0; ks < 4; ++ks){
      bf16x8 a = *(bf16x8*)(Ab + swz(wid * 16 + lr, (uint)(ks * 64 + lg * 16), 256));
      for (int cf = 0; cf < 8; ++cf){
        bf16x8 b = *(bf16x8*)(Bb + swz(cf * 16 + lr, (uint)(ks * 64 + lg * 16), 256));
        acc[cf] = __builtin_amdgcn_mfma_f32_16x16x32_bf16(a, b, acc[cf], 0, 0, 0);
      }
    }
    for (int cf = 0; cf < 8; ++cf){
      for (int i = 0; i < 4; i++){
        int row = wid * 16 + lg * 4 + i;
        int gr = n0 + row;
        if (gr >= NN) continue;
        int col = cf * 16 + lr;
        float v = acc[cf][i];
        if (chunk == 0)      q_n[(size_t)gr * 128 + col] = f2bf(v + bq[col]);
        else if (chunk == 1) kv[(size_t)gr * 256 + ((col >> 1) << 2) + (col & 1)]     = f2bf(v + bk[col]);
        else if (chunk == 2) kv[(size_t)gr * 256 + ((col >> 1) << 2) + 2 + (col & 1)] = f2bf(v + bv[col]);
        else                 out[(size_t)gr * 128 + col] = v + bsk[col];
      }
    }
  }
}

// ---------------- K2 v3p: streaming edge GEMM, software-pipelined msg prefetch -------
// A = We^T half (64 ch x K=256) in 128 VGPRs; B = edge features in registers.
// Pipeline: cos(B[0..3]) -> pack msg(B[4..7], consumes m) -> ISSUE next tile's msg
// loads -> 32 MFMA + store (loads fly under ~500 cyc of compute). m[] is dead after
// the pack, so no double-buffer and no VGPR growth (still 2 waves/SIMD).
__global__ __launch_bounds__(256, 2) void k_edge3(
    const float* __restrict__ rel, const float* __restrict__ msg,
    const float* __restrict__ tw, const float* __restrict__ tb,
    const ushort* __restrict__ Wet, ushort* __restrict__ ep){
  int tid = threadIdx.x;
  int wid = tid >> 6, l = tid & 63, lr = l & 15, lg = l >> 4;
  int gw = (int)blockIdx.x * 4 + wid;   // global wave id (8192 total)
  int half = gw & 1;                    // channel half: 0 -> ch 0..63, 1 -> ch 64..127
  bf16x8 Af[4][8];
  const char* WB = (const char*)Wet;
  #pragma unroll
  for (int rt = 0; rt < 4; ++rt)
    #pragma unroll
    for (int ks = 0; ks < 8; ++ks)
      Af[rt][ks] = *(const bf16x8*)(WB + (size_t)(half*64 + rt*16 + lr)*512 + ks*64 + lg*16);

  const int NG = EE / 16, stride = G_E3 * 2;
  int g = gw >> 1;
  float4 m[8]; float relN = 0.f;
  if (g < NG){ // prologue: issue tile-0 loads
    const float* MB = msg + (size_t)(g * 16 + lr) * 128 + lg * 8;
    #pragma unroll
    for (int ks = 0; ks < 4; ++ks){
      m[2*ks]   = *(const float4*)(MB + ks * 32);
      m[2*ks+1] = *(const float4*)(MB + ks * 32 + 4);
    }
    relN = rel[g * 16 + lr];
  }
  for (; g < NG; g += stride){
    int e0 = g * 16;
    float relv = relN;
    bf16x8 B[8];
    #pragma unroll
    for (int ks = 0; ks < 4; ++ks){     // k = ks*32 + lg*8 : cos features
      int k0 = ks * 32 + lg * 8;
      float4 wa = *(const float4*)(tw + k0), wb = *(const float4*)(tw + k0 + 4);
      float4 ba = *(const float4*)(tb + k0), bb = *(const float4*)(tb + k0 + 4);
      float c0 = __cosf(fmaf(relv, wa.x, ba.x));
      float c1 = __cosf(fmaf(relv, wa.y, ba.y));
      float c2 = __cosf(fmaf(relv, wa.z, ba.z));
      float c3 = __cosf(fmaf(relv, wa.w, ba.w));
      float c4 = __cosf(fmaf(relv, wb.x, bb.x));
      float c5 = __cosf(fmaf(relv, wb.y, bb.y));
      float c6 = __cosf(fmaf(relv, wb.z, bb.z));
      float c7 = __cosf(fmaf(relv, wb.w, bb.w));
      uint4 w; w.x = pack2(c0,c1); w.y = pack2(c2,c3); w.z = pack2(c4,c5); w.w = pack2(c6,c7);
      B[ks] = *(bf16x8*)&w;
    }
    #pragma unroll
    for (int ks = 0; ks < 4; ++ks){     // pack msg (vmcnt waits here); m dead after
      float4 a = m[2*ks], b = m[2*ks+1];
      uint4 w; w.x = pack2(a.x,a.y); w.y = pack2(a.z,a.w); w.z = pack2(b.x,b.y); w.w = pack2(b.z,b.w);
      B[4+ks] = *(bf16x8*)&w;
    }
    if (g + stride < NG){               // prefetch next tile: flies under MFMA+store
      const float* MB = msg + (size_t)((g + stride) * 16 + lr) * 128 + lg * 8;
      #pragma unroll
      for (int ks = 0; ks < 4; ++ks){
        m[2*ks]   = *(const float4*)(MB + ks * 32);
        m[2*ks+1] = *(const float4*)(MB + ks * 32 + 4);
      }
      relN = rel[(g + stride) * 16 + lr];
    }
    f32x4 acc[4];
    #pragma unroll
    for (int rt = 0; rt < 4; ++rt) acc[rt] = (f32x4){0.f,0.f,0.f,0.f};
    #pragma unroll
    for (int ks = 0; ks < 8; ++ks)
      #pragma unroll
      for (int rt = 0; rt < 4; ++rt)
        acc[rt] = __builtin_amdgcn_mfma_f32_16x16x32_bf16(Af[rt][ks], B[ks], acc[rt], 0, 0, 0);
    // D: col = lane&15 = edge, row = (lane>>4)*4+i = channel -> 4 contiguous ushorts
    #pragma unroll
    for (int rt = 0; rt < 4; ++rt){
      uint2 w = make_uint2(pack2(acc[rt][0], acc[rt][1]), pack2(acc[rt][2], acc[rt][3]));
      *(uint2*)(ep + (size_t)(e0 + lr) * 128 + half * 64 + rt * 16 + lg * 4) = w;
    }
  }
}

// ---------------- Sort: histogram -> 2-level exclusive scan -> placement --------------
__global__ void k_hist(const int* __restrict__ ei, int* __restrict__ deg){
  int e = blockIdx.x * 256 + threadIdx.x;
  if (e < EE) atomicAdd(&deg[ei[EE + e]], 1);
}

__global__ __launch_bounds__(256) void k_scan1(const int* __restrict__ deg,
                                               int* __restrict__ start,
                                               int* __restrict__ partial){
  __shared__ int sums[256];
  int b = blockIdx.x, tid = threadIdx.x;
  int base = b * 1024 + tid * 4;
  int d0 = (base + 0 < NN) ? deg[base + 0] : 0;
  int d1 = (base + 1 < NN) ? deg[base + 1] : 0;
  int d2 = (base + 2 < NN) ? deg[base + 2] : 0;
  int d3 = (base + 3 < NN) ? deg[base + 3] : 0;
  int s = d0 + d1 + d2 + d3;
  sums[tid] = s;
  __syncthreads();
  for (int off = 1; off < 256; off <<= 1){
    int v = (tid >= off) ? sums[tid - off] : 0;
    __syncthreads();
    sums[tid] += v;
    __syncthreads();
  }
  int excl = sums[tid] - s;
  if (base + 0 < NN) start[base + 0] = excl;
  if (base + 1 < NN) start[base + 1] = excl + d0;
  if (base + 2 < NN) start[base + 2] = excl + d0 + d1;
  if (base + 3 < NN) start[base + 3] = excl + d0 + d1 + d2;
  if (tid == 255) partial[b] = sums[255];
}

__global__ __launch_bounds__(128) void k_scan2(int* __restrict__ partial){
  __shared__ int s[128];
  int tid = threadIdx.x;
  int v = (tid < NB_SCAN) ? partial[tid] : 0;
  s[tid] = v;
  __syncthreads();
  for (int off = 1; off < 128; off <<= 1){
    int u = (tid >= off) ? s[tid - off] : 0;
    __syncthreads();
    s[tid] += u;
    __syncthreads();
  }
  if (tid < NB_SCAN) partial[tid] = s[tid] - v;  // exclusive
}

__global__ void k_scan3(int* __restrict__ start, const int* __restrict__ partial,
                        int* __restrict__ cursor){
  int i = blockIdx.x * 256 + threadIdx.x;
  if (i < NN){
    int v = start[i] + partial[i >> 10];
    start[i] = v;
    cursor[i] = v;
  }
  if (i == 0) start[NN] = EE;
}

// placement + rel fused (one pass over ei)
__global__ void k_place(const int* __restrict__ ei, const float* __restrict__ tt,
                        const float* __restrict__ lu, int* __restrict__ cursor,
                        uint2* __restrict__ sorted2, float* __restrict__ rel){
  int e = blockIdx.x * 256 + threadIdx.x;
  if (e < EE){
    int dst = ei[EE + e];
    int src = ei[e];
    rel[e] = tt[e] - lu[src];
    int pos = atomicAdd(&cursor[dst], 1);
    sorted2[pos] = make_uint2((uint)e, (uint)src);
  }
}

// ---------------- K3: per-node gather (shfl-batched indices, x4 MLP) ------------------
__global__ __launch_bounds__(256) void k_gather(
    const ushort* __restrict__ q_n, const ushort* __restrict__ kv,
    const ushort* __restrict__ ep, const int* __restrict__ start,
    const uint2* __restrict__ sorted2, float* __restrict__ out){
  int wave = (blockIdx.x * 256 + threadIdx.x) >> 6;
  if (wave >= NN) return;
  int n = wave;
  int l = threadIdx.x & 63;
  int c = l * 2;
  int s0 = start[n], s1 = start[n + 1];
  uint qq = *(const uint*)(q_n + (size_t)n * 128 + c);
  float q0 = bf2f(qq & 0xffff), q1 = bf2f(qq >> 16);
  float acc0 = 0.f, acc1 = 0.f, denom = 0.f;
  for (int base = s0; base < s1; base += 64){
    int chunk = s1 - base; if (chunk > 64) chunk = 64;
    uint2 myp = make_uint2(0u, 0u);
    if (l < chunk) myp = sorted2[base + l];
    int i = 0;
    for (; i + 4 <= chunk; i += 4){
      uint ia = __shfl(myp.x, i),     sa = __shfl(myp.y, i);
      uint ib = __shfl(myp.x, i + 1), sb = __shfl(myp.y, i + 1);
      uint ic = __shfl(myp.x, i + 2), sc = __shfl(myp.y, i + 2);
      uint id = __shfl(myp.x, i + 3), sd = __shfl(myp.y, i + 3);
      uint2 kv0 = *(const uint2*)(kv + (size_t)sa * 256 + c * 2);
      uint2 kv1 = *(const uint2*)(kv + (size_t)sb * 256 + c * 2);
      uint2 kv2 = *(const uint2*)(kv + (size_t)sc * 256 + c * 2);
      uint2 kv3 = *(const uint2*)(kv + (size_t)sd * 256 + c * 2);
      uint e0 = *(const uint*)(ep + (size_t)ia * 128 + c);
      uint e1 = *(const uint*)(ep + (size_t)ib * 128 + c);
      uint e2 = *(const uint*)(ep + (size_t)ic * 128 + c);
      uint e3 = *(const uint*)(ep + (size_t)id * 128 + c);
      float pa0 = bf2f(e0 & 0xffff), pa1 = bf2f(e0 >> 16);
      float pb0 = bf2f(e1 & 0xffff), pb1 = bf2f(e1 >> 16);
      float pc0 = bf2f(e2 & 0xffff), pc1 = bf2f(e2 >> 16);
      float pd0 = bf2f(e3 & 0xffff), pd1 = bf2f(e3 >> 16);
      float ka = q0 * (bf2f(kv0.x & 0xffff) + pa0) + q1 * (bf2f(kv0.x >> 16) + pa1);
      float kb = q0 * (bf2f(kv1.x & 0xffff) + pb0) + q1 * (bf2f(kv1.x >> 16) + pb1);
      float kc = q0 * (bf2f(kv2.x & 0xffff) + pc0) + q1 * (bf2f(kv2.x >> 16) + pc1);
      float kd = q0 * (bf2f(kv3.x & 0xffff) + pd0) + q1 * (bf2f(kv3.x >> 16) + pd1);
      #pragma unroll
      for (int off = 16; off > 0; off >>= 1){
        ka += __shfl_xor(ka, off);
        kb += __shfl_xor(kb, off);
        kc += __shfl_xor(kc, off);
        kd += __shfl_xor(kd, off);
      }
      float ea = __expf(ka * 0.125f), eb = __expf(kb * 0.125f);
      float ec = __expf(kc * 0.125f), ed = __expf(kd * 0.125f);
      denom += (ea + eb) + (ec + ed);
      acc0 += ea * (bf2f(kv0.y & 0xffff) + pa0) + eb * (bf2f(kv1.y & 0xffff) + pb0)
            + ec * (bf2f(kv2.y & 0xffff) + pc0) + ed * (bf2f(kv3.y & 0xffff) + pd0);
      acc1 += ea * (bf2f(kv0.y >> 16) + pa1) + eb * (bf2f(kv1.y >> 16) + pb1)
            + ec * (bf2f(kv2.y >> 16) + pc1) + ed * (bf2f(kv3.y >> 16) + pd1);
    }
    for (; i + 2 <= chunk; i += 2){
      uint ia = __shfl(myp.x, i),     sa = __shfl(myp.y, i);
      uint ib = __shfl(myp.x, i + 1), sb = __shfl(myp.y, i + 1);
      uint2 kv0 = *(const uint2*)(kv + (size_t)sa * 256 + c * 2);
      uint2 kv1 = *(const uint2*)(kv + (size_t)sb * 256 + c * 2);
      uint e0 = *(const uint*)(ep + (size_t)ia * 128 + c);
      uint e1 = *(const uint*)(ep + (size_t)ib * 128 + c);
      float pa0 = bf2f(e0 & 0xffff), pa1 = bf2f(e0 >> 16);
      float pb0 = bf2f(e1 & 0xffff), pb1 = bf2f(e1 >> 16);
      float ka = q0 * (bf2f(kv0.x & 0xffff) + pa0) + q1 * (bf2f(kv0.x >> 16) + pa1);
      float kb = q0 * (bf2f(kv1.x & 0xffff) + pb0) + q1 * (bf2f(kv1.x >> 16) + pb1);
      #pragma unroll
      for (int off = 16; off > 0; off >>= 1){
        ka += __shfl_xor(ka, off);
        kb += __shfl_xor(kb, off);
      }
      float ea = __expf(ka * 0.125f), eb = __expf(kb * 0.125f);
      denom += ea + eb;
      acc0 += ea * (bf2f(kv0.y & 0xffff) + pa0) + eb * (bf2f(kv1.y & 0xffff) + pb0);
      acc1 += ea * (bf2f(kv0.y >> 16) + pa1) + eb * (bf2f(kv1.y >> 16) + pb1);
    }
    if (i < chunk){
      uint ia = __shfl(myp.x, i), sa = __shfl(myp.y, i);
      uint2 kv0 = *(const uint2*)(kv + (size_t)sa * 256 + c * 2);
      uint e0 = *(const uint*)(ep + (size_t)ia * 128 + c);
      float pa0 = bf2f(e0 & 0xffff), pa1 = bf2f(e0 >> 16);
      float ka = q0 * (bf2f(kv0.x & 0xffff) + pa0) + q1 * (bf2f(kv0.x >> 16) + pa1);
      #pragma unroll
      for (int off = 16; off > 0; off >>= 1) ka += __shfl_xor(ka, off);
      float ea = __expf(ka * 0.125f);
      denom += ea;
      acc0 += ea * (bf2f(kv0.y & 0xffff) + pa0);
      acc1 += ea * (bf2f(kv0.y >> 16) + pa1);
    }
  }
  float inv = 1.0f / (denom + 1e-16f);
  size_t o = (size_t)n * 128 + c;
  out[o]     += acc0 * inv;
  out[o + 1] += acc1 * inv;
}

extern "C" void kernel_launch(void* const* d_in, const int* in_sizes, int n_in,
                              void* d_out, int out_size, void* d_ws, size_t ws_size,
                              hipStream_t stream) {
  const float* x   = (const float*)d_in[0];
  const float* lu  = (const float*)d_in[1];
  const float* t   = (const float*)d_in[2];
  const float* msg = (const float*)d_in[3];
  const float* tw  = (const float*)d_in[4];
  const float* tb  = (const float*)d_in[5];
  const float* Wq  = (const float*)d_in[6];
  const float* bq  = (const float*)d_in[7];
  const float* Wk  = (const float*)d_in[8];
  const float* bk  = (const float*)d_in[9];
  const float* Wv  = (const float*)d_in[10];
  const float* bv  = (const float*)d_in[11];
  const float* We  = (const float*)d_in[12];
  const float* Wsk = (const float*)d_in[13];
  const float* bsk = (const float*)d_in[14];
  const int*   ei  = (const int*)d_in[15];
  float* out = (float*)d_out;

  char* w = (char*)d_ws;
  size_t off = 0;
  auto nxt = [&](size_t b){ size_t r = off; off += (b + 255) & ~(size_t)255; return r; };
  ushort* q_n   = (ushort*)(w + nxt((size_t)NN * 128 * 2));
  ushort* kv    = (ushort*)(w + nxt((size_t)NN * 256 * 2));
  ushort* epj   = (ushort*)(w + nxt((size_t)EE * 128 * 2));
  ushort* W4t   = (ushort*)(w + nxt((size_t)512 * 128 * 2));
  ushort* Wet   = (ushort*)(w + nxt((size_t)128 * 256 * 2));
  int* deg      = (int*)(w + nxt((size_t)NN * 4));
  int* start    = (int*)(w + nxt((size_t)(NN + 1) * 4));
  int* cursor   = (int*)(w + nxt((size_t)NN * 4));
  int* partial  = (int*)(w + nxt((size_t)(NB_SCAN + 1) * 4));
  uint2* sorted2 = (uint2*)(w + nxt((size_t)EE * 8));
  float* rel    = (float*)(w + nxt((size_t)EE * 4));

  k_prep<<<(NN + 255) / 256, 256, 0, stream>>>(Wq, Wk, Wv, Wsk, We, W4t, Wet, deg);
  k_node<<<(NN + 63) / 64, 256, 0, stream>>>(x, W4t, bq, bk, bv, bsk, q_n, kv, out);
  k_hist<<<(EE + 255) / 256, 256, 0, stream>>>(ei, deg);
  k_scan1<<<NB_SCAN, 256, 0, stream>>>(deg, start, partial);
  k_scan2<<<1, 128, 0, stream>>>(partial);
  k_scan3<<<(NN + 255) / 256, 256, 0, stream>>>(start, partial, cursor);
  k_place<<<(EE + 255) / 256, 256, 0, stream>>>(ei, t, lu, cursor, sorted2, rel);
  k_edge3<<<G_E3, 256, 0, stream>>>(rel, msg, tw, tb, Wet, epj);
  k_gather<<<(NN * 64 + 255) / 256, 256, 0, stream>>>(q_n, kv, epj, start, sorted2, out);
}

// Round 13
// 561.758 us; speedup vs baseline: 1.0051x; 1.0051x over previous
//
#include <hip/hip_runtime.h>
#include <hip/hip_bf16.h>

#define NN 100000
#define EE 640000
#define NB_SCAN 98   // ceil(NN/1024)
#define G_E3 2048    // k_edge3 blocks (8192 waves; 40000 tile-pairs)

typedef short bf16x8 __attribute__((ext_vector_type(8)));
typedef float f32x4 __attribute__((ext_vector_type(4)));

__device__ __forceinline__ ushort f2bf(float f){
  uint u = __float_as_uint(f);
  u += 0x7fffu + ((u >> 16) & 1u);   // round-to-nearest-even
  return (ushort)(u >> 16);
}
__device__ __forceinline__ float bf2f(ushort s){ return __uint_as_float(((uint)s) << 16); }
__device__ __forceinline__ uint pack2(float a, float b){ return ((uint)f2bf(b) << 16) | (uint)f2bf(a); }
__device__ __forceinline__ uint swz(uint row, uint colB, uint strideB){
  return row * strideB + (colB ^ ((row & 7u) << 4));
}

// ---------------- K0: weight prep (fp32 -> bf16, transposed [col][k]) + zero deg -----
__global__ void k_prep(const float* __restrict__ Wq, const float* __restrict__ Wk,
                       const float* __restrict__ Wv, const float* __restrict__ Wsk,
                       const float* __restrict__ We,
                       ushort* __restrict__ W4t, ushort* __restrict__ Wet,
                       int* __restrict__ deg){
  int tid = blockIdx.x * 256 + threadIdx.x;
  if (tid < 512 * 128){              // W4t[col 0..511][k 0..127], cols: q|k|v|skip
    int col = tid >> 7, k = tid & 127;
    const float* W = (col < 128) ? Wq : ((col < 256) ? Wk : ((col < 384) ? Wv : Wsk));
    W4t[tid] = f2bf(W[k * 128 + (col & 127)]);
  }
  if (tid < 128 * 256){              // Wet[col 0..127][k 0..255]
    int col = tid >> 8, k = tid & 255;
    Wet[tid] = f2bf(We[k * 128 + col]);
  }
  if (tid < NN) deg[tid] = 0;
}

// ---------------- K1: node GEMM x@[Wq|Wk|Wv|Wskip], 64-row tiles, bf16 MFMA ----------
__global__ __launch_bounds__(256) void k_node(
    const float* __restrict__ x, const ushort* __restrict__ W4t,
    const float* __restrict__ bq, const float* __restrict__ bk,
    const float* __restrict__ bv, const float* __restrict__ bsk,
    ushort* __restrict__ q_n, ushort* __restrict__ kv,
    float* __restrict__ out){
  __shared__ ushort As[64 * 128];
  __shared__ ushort Bs[128 * 128];
  char* Ab = (char*)As; char* Bb = (char*)Bs;
  int tid = threadIdx.x;
  int n0 = blockIdx.x * 64;
  {
    int row = tid >> 2, part = tid & 3;
    int gr = n0 + row;
    for (int j = 0; j < 4; j++){
      float4 a = make_float4(0.f,0.f,0.f,0.f), b = a;
      if (gr < NN){
        const float4* p = (const float4*)(x + (size_t)gr * 128 + part * 32 + j * 8);
        a = p[0]; b = p[1];
      }
      uint4 w; w.x = pack2(a.x,a.y); w.y = pack2(a.z,a.w); w.z = pack2(b.x,b.y); w.w = pack2(b.z,b.w);
      *(uint4*)(Ab + swz(row, (uint)(part * 64 + j * 16), 256)) = w;
    }
  }
  int wid = tid >> 6, l = tid & 63, lr = l & 15, lg = l >> 4;
  for (int chunk = 0; chunk < 4; ++chunk){
    if (chunk) __syncthreads();
    {
      int row = tid >> 1, half = tid & 1;
      const ushort* src = W4t + (size_t)(chunk * 128 + row) * 128 + half * 64;
      for (int j = 0; j < 8; j++){
        uint4 w = *(const uint4*)(src + j * 8);
        *(uint4*)(Bb + swz(row, (uint)(half * 128 + j * 16), 256)) = w;
      }
    }
    __syncthreads();
    f32x4 acc[8];
    for (int i = 0; i < 8; i++) acc[i] = (f32x4){0.f,0.f,0.f,0.f};
    for (int ks = 0; ks < 4; ++ks){
      bf16x8 a = *(bf16x8*)(Ab + swz(wid * 16 + lr, (uint)(ks * 64 + lg * 16), 256));
      for (int cf = 0; cf < 8; ++cf){
        bf16x8 b = *(bf16x8*)(Bb + swz(cf * 16 + lr, (uint)(ks * 64 + lg * 16), 256));
        acc[cf] = __builtin_amdgcn_mfma_f32_16x16x32_bf16(a, b, acc[cf], 0, 0, 0);
      }
    }
    for (int cf = 0; cf < 8; ++cf){
      for (int i = 0; i < 4; i++){
        int row = wid * 16 + lg * 4 + i;
        int gr = n0 + row;
        if (gr >= NN) continue;
        int col = cf * 16 + lr;
        float v = acc[cf][i];
        if (chunk == 0)      q_n[(size_t)gr * 128 + col] = f2bf(v + bq[col]);
        else if (chunk == 1) kv[(size_t)gr * 256 + ((col >> 1) << 2) + (col & 1)]     = f2bf(v + bk[col]);
        else if (chunk == 2) kv[(size_t)gr * 256 + ((col >> 1) << 2) + 2 + (col & 1)] = f2bf(v + bv[col]);
        else                 out[(size_t)gr * 128 + col] = v + bsk[col];
      }
    }
  }
}

// ---------------- K2 v3p2: pipelined edge GEMM, occupancy PINNED at 2 waves/EU -------
// Same rotated loop as R12 (prefetch next msg tile before the MFMA block), but
// amdgpu_waves_per_eu(2,2) stops the allocator from targeting 4 waves/SIMD and
// spilling the ~200-VGPR live state (R12: VGPR=128, +70MB spill writes).
__global__ __launch_bounds__(256)
__attribute__((amdgpu_waves_per_eu(2, 2)))
void k_edge3(
    const float* __restrict__ rel, const float* __restrict__ msg,
    const float* __restrict__ tw, const float* __restrict__ tb,
    const ushort* __restrict__ Wet, ushort* __restrict__ ep){
  int tid = threadIdx.x;
  int wid = tid >> 6, l = tid & 63, lr = l & 15, lg = l >> 4;
  int gw = (int)blockIdx.x * 4 + wid;   // global wave id (8192 total)
  int half = gw & 1;                    // channel half: 0 -> ch 0..63, 1 -> ch 64..127
  bf16x8 Af[4][8];
  const char* WB = (const char*)Wet;
  #pragma unroll
  for (int rt = 0; rt < 4; ++rt)
    #pragma unroll
    for (int ks = 0; ks < 8; ++ks)
      Af[rt][ks] = *(const bf16x8*)(WB + (size_t)(half*64 + rt*16 + lr)*512 + ks*64 + lg*16);

  const int NG = EE / 16, stride = G_E3 * 2;
  int g = gw >> 1;
  float4 m[8]; float relN = 0.f;
  if (g < NG){ // prologue: issue tile-0 loads
    const float* MB = msg + (size_t)(g * 16 + lr) * 128 + lg * 8;
    #pragma unroll
    for (int ks = 0; ks < 4; ++ks){
      m[2*ks]   = *(const float4*)(MB + ks * 32);
      m[2*ks+1] = *(const float4*)(MB + ks * 32 + 4);
    }
    relN = rel[g * 16 + lr];
  }
  for (; g < NG; g += stride){
    int e0 = g * 16;
    float relv = relN;
    bf16x8 B[8];
    #pragma unroll
    for (int ks = 0; ks < 4; ++ks){     // k = ks*32 + lg*8 : cos features
      int k0 = ks * 32 + lg * 8;
      float4 wa = *(const float4*)(tw + k0), wb = *(const float4*)(tw + k0 + 4);
      float4 ba = *(const float4*)(tb + k0), bb = *(const float4*)(tb + k0 + 4);
      float c0 = __cosf(fmaf(relv, wa.x, ba.x));
      float c1 = __cosf(fmaf(relv, wa.y, ba.y));
      float c2 = __cosf(fmaf(relv, wa.z, ba.z));
      float c3 = __cosf(fmaf(relv, wa.w, ba.w));
      float c4 = __cosf(fmaf(relv, wb.x, bb.x));
      float c5 = __cosf(fmaf(relv, wb.y, bb.y));
      float c6 = __cosf(fmaf(relv, wb.z, bb.z));
      float c7 = __cosf(fmaf(relv, wb.w, bb.w));
      uint4 w; w.x = pack2(c0,c1); w.y = pack2(c2,c3); w.z = pack2(c4,c5); w.w = pack2(c6,c7);
      B[ks] = *(bf16x8*)&w;
    }
    #pragma unroll
    for (int ks = 0; ks < 4; ++ks){     // pack msg (vmcnt waits here); m dead after
      float4 a = m[2*ks], b = m[2*ks+1];
      uint4 w; w.x = pack2(a.x,a.y); w.y = pack2(a.z,a.w); w.z = pack2(b.x,b.y); w.w = pack2(b.z,b.w);
      B[4+ks] = *(bf16x8*)&w;
    }
    if (g + stride < NG){               // prefetch next tile: flies under MFMA+store
      const float* MB = msg + (size_t)((g + stride) * 16 + lr) * 128 + lg * 8;
      #pragma unroll
      for (int ks = 0; ks < 4; ++ks){
        m[2*ks]   = *(const float4*)(MB + ks * 32);
        m[2*ks+1] = *(const float4*)(MB + ks * 32 + 4);
      }
      relN = rel[(g + stride) * 16 + lr];
    }
    f32x4 acc[4];
    #pragma unroll
    for (int rt = 0; rt < 4; ++rt) acc[rt] = (f32x4){0.f,0.f,0.f,0.f};
    #pragma unroll
    for (int ks = 0; ks < 8; ++ks)
      #pragma unroll
      for (int rt = 0; rt < 4; ++rt)
        acc[rt] = __builtin_amdgcn_mfma_f32_16x16x32_bf16(Af[rt][ks], B[ks], acc[rt], 0, 0, 0);
    // D: col = lane&15 = edge, row = (lane>>4)*4+i = channel -> 4 contiguous ushorts
    #pragma unroll
    for (int rt = 0; rt < 4; ++rt){
      uint2 w = make_uint2(pack2(acc[rt][0], acc[rt][1]), pack2(acc[rt][2], acc[rt][3]));
      *(uint2*)(ep + (size_t)(e0 + lr) * 128 + half * 64 + rt * 16 + lg * 4) = w;
    }
  }
}

// ---------------- Sort: histogram -> 2-level exclusive scan -> placement --------------
__global__ void k_hist(const int* __restrict__ ei, int* __restrict__ deg){
  int e = blockIdx.x * 256 + threadIdx.x;
  if (e < EE) atomicAdd(&deg[ei[EE + e]], 1);
}

__global__ __launch_bounds__(256) void k_scan1(const int* __restrict__ deg,
                                               int* __restrict__ start,
                                               int* __restrict__ partial){
  __shared__ int sums[256];
  int b = blockIdx.x, tid = threadIdx.x;
  int base = b * 1024 + tid * 4;
  int d0 = (base + 0 < NN) ? deg[base + 0] : 0;
  int d1 = (base + 1 < NN) ? deg[base + 1] : 0;
  int d2 = (base + 2 < NN) ? deg[base + 2] : 0;
  int d3 = (base + 3 < NN) ? deg[base + 3] : 0;
  int s = d0 + d1 + d2 + d3;
  sums[tid] = s;
  __syncthreads();
  for (int off = 1; off < 256; off <<= 1){
    int v = (tid >= off) ? sums[tid - off] : 0;
    __syncthreads();
    sums[tid] += v;
    __syncthreads();
  }
  int excl = sums[tid] - s;
  if (base + 0 < NN) start[base + 0] = excl;
  if (base + 1 < NN) start[base + 1] = excl + d0;
  if (base + 2 < NN) start[base + 2] = excl + d0 + d1;
  if (base + 3 < NN) start[base + 3] = excl + d0 + d1 + d2;
  if (tid == 255) partial[b] = sums[255];
}

__global__ __launch_bounds__(128) void k_scan2(int* __restrict__ partial){
  __shared__ int s[128];
  int tid = threadIdx.x;
  int v = (tid < NB_SCAN) ? partial[tid] : 0;
  s[tid] = v;
  __syncthreads();
  for (int off = 1; off < 128; off <<= 1){
    int u = (tid >= off) ? s[tid - off] : 0;
    __syncthreads();
    s[tid] += u;
    __syncthreads();
  }
  if (tid < NB_SCAN) partial[tid] = s[tid] - v;  // exclusive
}

__global__ void k_scan3(int* __restrict__ start, const int* __restrict__ partial,
                        int* __restrict__ cursor){
  int i = blockIdx.x * 256 + threadIdx.x;
  if (i < NN){
    int v = start[i] + partial[i >> 10];
    start[i] = v;
    cursor[i] = v;
  }
  if (i == 0) start[NN] = EE;
}

// placement + rel fused (one pass over ei)
__global__ void k_place(const int* __restrict__ ei, const float* __restrict__ tt,
                        const float* __restrict__ lu, int* __restrict__ cursor,
                        uint2* __restrict__ sorted2, float* __restrict__ rel){
  int e = blockIdx.x * 256 + threadIdx.x;
  if (e < EE){
    int dst = ei[EE + e];
    int src = ei[e];
    rel[e] = tt[e] - lu[src];
    int pos = atomicAdd(&cursor[dst], 1);
    sorted2[pos] = make_uint2((uint)e, (uint)src);
  }
}

// ---------------- K3: per-node gather (shfl-batched indices, x4 MLP) ------------------
__global__ __launch_bounds__(256) void k_gather(
    const ushort* __restrict__ q_n, const ushort* __restrict__ kv,
    const ushort* __restrict__ ep, const int* __restrict__ start,
    const uint2* __restrict__ sorted2, float* __restrict__ out){
  int wave = (blockIdx.x * 256 + threadIdx.x) >> 6;
  if (wave >= NN) return;
  int n = wave;
  int l = threadIdx.x & 63;
  int c = l * 2;
  int s0 = start[n], s1 = start[n + 1];
  uint qq = *(const uint*)(q_n + (size_t)n * 128 + c);
  float q0 = bf2f(qq & 0xffff), q1 = bf2f(qq >> 16);
  float acc0 = 0.f, acc1 = 0.f, denom = 0.f;
  for (int base = s0; base < s1; base += 64){
    int chunk = s1 - base; if (chunk > 64) chunk = 64;
    uint2 myp = make_uint2(0u, 0u);
    if (l < chunk) myp = sorted2[base + l];
    int i = 0;
    for (; i + 4 <= chunk; i += 4){
      uint ia = __shfl(myp.x, i),     sa = __shfl(myp.y, i);
      uint ib = __shfl(myp.x, i + 1), sb = __shfl(myp.y, i + 1);
      uint ic = __shfl(myp.x, i + 2), sc = __shfl(myp.y, i + 2);
      uint id = __shfl(myp.x, i + 3), sd = __shfl(myp.y, i + 3);
      uint2 kv0 = *(const uint2*)(kv + (size_t)sa * 256 + c * 2);
      uint2 kv1 = *(const uint2*)(kv + (size_t)sb * 256 + c * 2);
      uint2 kv2 = *(const uint2*)(kv + (size_t)sc * 256 + c * 2);
      uint2 kv3 = *(const uint2*)(kv + (size_t)sd * 256 + c * 2);
      uint e0 = *(const uint*)(ep + (size_t)ia * 128 + c);
      uint e1 = *(const uint*)(ep + (size_t)ib * 128 + c);
      uint e2 = *(const uint*)(ep + (size_t)ic * 128 + c);
      uint e3 = *(const uint*)(ep + (size_t)id * 128 + c);
      float pa0 = bf2f(e0 & 0xffff), pa1 = bf2f(e0 >> 16);
      float pb0 = bf2f(e1 & 0xffff), pb1 = bf2f(e1 >> 16);
      float pc0 = bf2f(e2 & 0xffff), pc1 = bf2f(e2 >> 16);
      float pd0 = bf2f(e3 & 0xffff), pd1 = bf2f(e3 >> 16);
      float ka = q0 * (bf2f(kv0.x & 0xffff) + pa0) + q1 * (bf2f(kv0.x >> 16) + pa1);
      float kb = q0 * (bf2f(kv1.x & 0xffff) + pb0) + q1 * (bf2f(kv1.x >> 16) + pb1);
      float kc = q0 * (bf2f(kv2.x & 0xffff) + pc0) + q1 * (bf2f(kv2.x >> 16) + pc1);
      float kd = q0 * (bf2f(kv3.x & 0xffff) + pd0) + q1 * (bf2f(kv3.x >> 16) + pd1);
      #pragma unroll
      for (int off = 16; off > 0; off >>= 1){
        ka += __shfl_xor(ka, off);
        kb += __shfl_xor(kb, off);
        kc += __shfl_xor(kc, off);
        kd += __shfl_xor(kd, off);
      }
      float ea = __expf(ka * 0.125f), eb = __expf(kb * 0.125f);
      float ec = __expf(kc * 0.125f), ed = __expf(kd * 0.125f);
      denom += (ea + eb) + (ec + ed);
      acc0 += ea * (bf2f(kv0.y & 0xffff) + pa0) + eb * (bf2f(kv1.y & 0xffff) + pb0)
            + ec * (bf2f(kv2.y & 0xffff) + pc0) + ed * (bf2f(kv3.y & 0xffff) + pd0);
      acc1 += ea * (bf2f(kv0.y >> 16) + pa1) + eb * (bf2f(kv1.y >> 16) + pb1)
            + ec * (bf2f(kv2.y >> 16) + pc1) + ed * (bf2f(kv3.y >> 16) + pd1);
    }
    for (; i + 2 <= chunk; i += 2){
      uint ia = __shfl(myp.x, i),     sa = __shfl(myp.y, i);
      uint ib = __shfl(myp.x, i + 1), sb = __shfl(myp.y, i + 1);
      uint2 kv0 = *(const uint2*)(kv + (size_t)sa * 256 + c * 2);
      uint2 kv1 = *(const uint2*)(kv + (size_t)sb * 256 + c * 2);
      uint e0 = *(const uint*)(ep + (size_t)ia * 128 + c);
      uint e1 = *(const uint*)(ep + (size_t)ib * 128 + c);
      float pa0 = bf2f(e0 & 0xffff), pa1 = bf2f(e0 >> 16);
      float pb0 = bf2f(e1 & 0xffff), pb1 = bf2f(e1 >> 16);
      float ka = q0 * (bf2f(kv0.x & 0xffff) + pa0) + q1 * (bf2f(kv0.x >> 16) + pa1);
      float kb = q0 * (bf2f(kv1.x & 0xffff) + pb0) + q1 * (bf2f(kv1.x >> 16) + pb1);
      #pragma unroll
      for (int off = 16; off > 0; off >>= 1){
        ka += __shfl_xor(ka, off);
        kb += __shfl_xor(kb, off);
      }
      float ea = __expf(ka * 0.125f), eb = __expf(kb * 0.125f);
      denom += ea + eb;
      acc0 += ea * (bf2f(kv0.y & 0xffff) + pa0) + eb * (bf2f(kv1.y & 0xffff) + pb0);
      acc1 += ea * (bf2f(kv0.y >> 16) + pa1) + eb * (bf2f(kv1.y >> 16) + pb1);
    }
    if (i < chunk){
      uint ia = __shfl(myp.x, i), sa = __shfl(myp.y, i);
      uint2 kv0 = *(const uint2*)(kv + (size_t)sa * 256 + c * 2);
      uint e0 = *(const uint*)(ep + (size_t)ia * 128 + c);
      float pa0 = bf2f(e0 & 0xffff), pa1 = bf2f(e0 >> 16);
      float ka = q0 * (bf2f(kv0.x & 0xffff) + pa0) + q1 * (bf2f(kv0.x >> 16) + pa1);
      #pragma unroll
      for (int off = 16; off > 0; off >>= 1) ka += __shfl_xor(ka, off);
      float ea = __expf(ka * 0.125f);
      denom += ea;
      acc0 += ea * (bf2f(kv0.y & 0xffff) + pa0);
      acc1 += ea * (bf2f(kv0.y >> 16) + pa1);
    }
  }
  float inv = 1.0f / (denom + 1e-16f);
  size_t o = (size_t)n * 128 + c;
  out[o]     += acc0 * inv;
  out[o + 1] += acc1 * inv;
}

extern "C" void kernel_launch(void* const* d_in, const int* in_sizes, int n_in,
                              void* d_out, int out_size, void* d_ws, size_t ws_size,
                              hipStream_t stream) {
  const float* x   = (const float*)d_in[0];
  const float* lu  = (const float*)d_in[1];
  const float* t   = (const float*)d_in[2];
  const float* msg = (const float*)d_in[3];
  const float* tw  = (const float*)d_in[4];
  const float* tb  = (const float*)d_in[5];
  const float* Wq  = (const float*)d_in[6];
  const float* bq  = (const float*)d_in[7];
  const float* Wk  = (const float*)d_in[8];
  const float* bk  = (const float*)d_in[9];
  const float* Wv  = (const float*)d_in[10];
  const float* bv  = (const float*)d_in[11];
  const float* We  = (const float*)d_in[12];
  const float* Wsk = (const float*)d_in[13];
  const float* bsk = (const float*)d_in[14];
  const int*   ei  = (const int*)d_in[15];
  float* out = (float*)d_out;

  char* w = (char*)d_ws;
  size_t off = 0;
  auto nxt = [&](size_t b){ size_t r = off; off += (b + 255) & ~(size_t)255; return r; };
  ushort* q_n   = (ushort*)(w + nxt((size_t)NN * 128 * 2));
  ushort* kv    = (ushort*)(w + nxt((size_t)NN * 256 * 2));
  ushort* epj   = (ushort*)(w + nxt((size_t)EE * 128 * 2));
  ushort* W4t   = (ushort*)(w + nxt((size_t)512 * 128 * 2));
  ushort* Wet   = (ushort*)(w + nxt((size_t)128 * 256 * 2));
  int* deg      = (int*)(w + nxt((size_t)NN * 4));
  int* start    = (int*)(w + nxt((size_t)(NN + 1) * 4));
  int* cursor   = (int*)(w + nxt((size_t)NN * 4));
  int* partial  = (int*)(w + nxt((size_t)(NB_SCAN + 1) * 4));
  uint2* sorted2 = (uint2*)(w + nxt((size_t)EE * 8));
  float* rel    = (float*)(w + nxt((size_t)EE * 4));

  k_prep<<<(NN + 255) / 256, 256, 0, stream>>>(Wq, Wk, Wv, Wsk, We, W4t, Wet, deg);
  k_node<<<(NN + 63) / 64, 256, 0, stream>>>(x, W4t, bq, bk, bv, bsk, q_n, kv, out);
  k_hist<<<(EE + 255) / 256, 256, 0, stream>>>(ei, deg);
  k_scan1<<<NB_SCAN, 256, 0, stream>>>(deg, start, partial);
  k_scan2<<<1, 128, 0, stream>>>(partial);
  k_scan3<<<(NN + 255) / 256, 256, 0, stream>>>(start, partial, cursor);
  k_place<<<(EE + 255) / 256, 256, 0, stream>>>(ei, t, lu, cursor, sorted2, rel);
  k_edge3<<<G_E3, 256, 0, stream>>>(rel, msg, tw, tb, Wet, epj);
  k_gather<<<(NN * 64 + 255) / 256, 256, 0, stream>>>(q_n, kv, epj, start, sorted2, out);
}

// Round 14
// 464.763 us; speedup vs baseline: 1.2148x; 1.2087x over previous
//
#include <hip/hip_runtime.h>
#include <hip/hip_bf16.h>

#define NN 100000
#define EE 640000
#define NB_SCAN 98   // ceil(NN/1024)
#define G_E3 2048    // k_edge3 blocks (8192 waves; 40000 tile-pairs)

typedef short bf16x8 __attribute__((ext_vector_type(8)));
typedef float f32x4 __attribute__((ext_vector_type(4)));

__device__ __forceinline__ ushort f2bf(float f){
  uint u = __float_as_uint(f);
  u += 0x7fffu + ((u >> 16) & 1u);   // round-to-nearest-even
  return (ushort)(u >> 16);
}
__device__ __forceinline__ float bf2f(ushort s){ return __uint_as_float(((uint)s) << 16); }
__device__ __forceinline__ uint pack2(float a, float b){ return ((uint)f2bf(b) << 16) | (uint)f2bf(a); }
__device__ __forceinline__ uint swz(uint row, uint colB, uint strideB){
  return row * strideB + (colB ^ ((row & 7u) << 4));
}

// ---------------- K0: weight prep (fp32 -> bf16, transposed [col][k]) + zero deg -----
__global__ void k_prep(const float* __restrict__ Wq, const float* __restrict__ Wk,
                       const float* __restrict__ Wv, const float* __restrict__ Wsk,
                       const float* __restrict__ We,
                       ushort* __restrict__ W4t, ushort* __restrict__ Wet,
                       int* __restrict__ deg){
  int tid = blockIdx.x * 256 + threadIdx.x;
  if (tid < 512 * 128){              // W4t[col 0..511][k 0..127], cols: q|k|v|skip
    int col = tid >> 7, k = tid & 127;
    const float* W = (col < 128) ? Wq : ((col < 256) ? Wk : ((col < 384) ? Wv : Wsk));
    W4t[tid] = f2bf(W[k * 128 + (col & 127)]);
  }
  if (tid < 128 * 256){              // Wet[col 0..127][k 0..255]
    int col = tid >> 8, k = tid & 255;
    Wet[tid] = f2bf(We[k * 128 + col]);
  }
  if (tid < NN) deg[tid] = 0;
}

// ---------------- K1: node GEMM x@[Wq|Wk|Wv|Wskip], 64-row tiles, bf16 MFMA ----------
__global__ __launch_bounds__(256) void k_node(
    const float* __restrict__ x, const ushort* __restrict__ W4t,
    const float* __restrict__ bq, const float* __restrict__ bk,
    const float* __restrict__ bv, const float* __restrict__ bsk,
    ushort* __restrict__ q_n, ushort* __restrict__ kv,
    float* __restrict__ out){
  __shared__ ushort As[64 * 128];
  __shared__ ushort Bs[128 * 128];
  char* Ab = (char*)As; char* Bb = (char*)Bs;
  int tid = threadIdx.x;
  int n0 = blockIdx.x * 64;
  {
    int row = tid >> 2, part = tid & 3;
    int gr = n0 + row;
    for (int j = 0; j < 4; j++){
      float4 a = make_float4(0.f,0.f,0.f,0.f), b = a;
      if (gr < NN){
        const float4* p = (const float4*)(x + (size_t)gr * 128 + part * 32 + j * 8);
        a = p[0]; b = p[1];
      }
      uint4 w; w.x = pack2(a.x,a.y); w.y = pack2(a.z,a.w); w.z = pack2(b.x,b.y); w.w = pack2(b.z,b.w);
      *(uint4*)(Ab + swz(row, (uint)(part * 64 + j * 16), 256)) = w;
    }
  }
  int wid = tid >> 6, l = tid & 63, lr = l & 15, lg = l >> 4;
  for (int chunk = 0; chunk < 4; ++chunk){
    if (chunk) __syncthreads();
    {
      int row = tid >> 1, half = tid & 1;
      const ushort* src = W4t + (size_t)(chunk * 128 + row) * 128 + half * 64;
      for (int j = 0; j < 8; j++){
        uint4 w = *(const uint4*)(src + j * 8);
        *(uint4*)(Bb + swz(row, (uint)(half * 128 + j * 16), 256)) = w;
      }
    }
    __syncthreads();
    f32x4 acc[8];
    for (int i = 0; i < 8; i++) acc[i] = (f32x4){0.f,0.f,0.f,0.f};
    for (int ks = 0; ks < 4; ++ks){
      bf16x8 a = *(bf16x8*)(Ab + swz(wid * 16 + lr, (uint)(ks * 64 + lg * 16), 256));
      for (int cf = 0; cf < 8; ++cf){
        bf16x8 b = *(bf16x8*)(Bb + swz(cf * 16 + lr, (uint)(ks * 64 + lg * 16), 256));
        acc[cf] = __builtin_amdgcn_mfma_f32_16x16x32_bf16(a, b, acc[cf], 0, 0, 0);
      }
    }
    for (int cf = 0; cf < 8; ++cf){
      for (int i = 0; i < 4; i++){
        int row = wid * 16 + lg * 4 + i;
        int gr = n0 + row;
        if (gr >= NN) continue;
        int col = cf * 16 + lr;
        float v = acc[cf][i];
        if (chunk == 0)      q_n[(size_t)gr * 128 + col] = f2bf(v + bq[col]);
        else if (chunk == 1) kv[(size_t)gr * 256 + ((col >> 1) << 2) + (col & 1)]     = f2bf(v + bk[col]);
        else if (chunk == 2) kv[(size_t)gr * 256 + ((col >> 1) << 2) + 2 + (col & 1)] = f2bf(v + bv[col]);
        else                 out[(size_t)gr * 128 + col] = v + bsk[col];
      }
    }
  }
}

// ---------------- K2 v3 (proven best, R9/R11 config): streaming edge GEMM ------------
// A = We^T half (64 ch x K=256) in 128 VGPRs; B = edge features in registers
// (lane lr = edge, lg = k-octet): k<128 cos, k>=128 msg direct row slice.
// Loads at iteration top; cos covers part of the latency; 2 waves/SIMD TLP covers
// the rest. Pipelined variants (R12/R13) spill — allocator caps at 128 VGPR.
__global__ __launch_bounds__(256, 2) void k_edge3(
    const float* __restrict__ rel, const float* __restrict__ msg,
    const float* __restrict__ tw, const float* __restrict__ tb,
    const ushort* __restrict__ Wet, ushort* __restrict__ ep){
  int tid = threadIdx.x;
  int wid = tid >> 6, l = tid & 63, lr = l & 15, lg = l >> 4;
  int gw = (int)blockIdx.x * 4 + wid;   // global wave id (8192 total)
  int half = gw & 1;                    // channel half: 0 -> ch 0..63, 1 -> ch 64..127
  bf16x8 Af[4][8];
  const char* WB = (const char*)Wet;
  #pragma unroll
  for (int rt = 0; rt < 4; ++rt)
    #pragma unroll
    for (int ks = 0; ks < 8; ++ks)
      Af[rt][ks] = *(const bf16x8*)(WB + (size_t)(half*64 + rt*16 + lr)*512 + ks*64 + lg*16);

  for (int g = gw >> 1; g < EE/16; g += G_E3 * 2){
    int e0 = g * 16;
    float4 m[8];
    const float* MB = msg + (size_t)(e0 + lr) * 128 + lg * 8;
    #pragma unroll
    for (int ks = 0; ks < 4; ++ks){
      m[2*ks]   = *(const float4*)(MB + ks * 32);
      m[2*ks+1] = *(const float4*)(MB + ks * 32 + 4);
    }
    float relv = rel[e0 + lr];
    bf16x8 B[8];
    #pragma unroll
    for (int ks = 0; ks < 4; ++ks){     // k = ks*32 + lg*8 : cos features
      int k0 = ks * 32 + lg * 8;
      float4 wa = *(const float4*)(tw + k0), wb = *(const float4*)(tw + k0 + 4);
      float4 ba = *(const float4*)(tb + k0), bb = *(const float4*)(tb + k0 + 4);
      float c0 = __cosf(fmaf(relv, wa.x, ba.x));
      float c1 = __cosf(fmaf(relv, wa.y, ba.y));
      float c2 = __cosf(fmaf(relv, wa.z, ba.z));
      float c3 = __cosf(fmaf(relv, wa.w, ba.w));
      float c4 = __cosf(fmaf(relv, wb.x, bb.x));
      float c5 = __cosf(fmaf(relv, wb.y, bb.y));
      float c6 = __cosf(fmaf(relv, wb.z, bb.z));
      float c7 = __cosf(fmaf(relv, wb.w, bb.w));
      uint4 w; w.x = pack2(c0,c1); w.y = pack2(c2,c3); w.z = pack2(c4,c5); w.w = pack2(c6,c7);
      B[ks] = *(bf16x8*)&w;
    }
    #pragma unroll
    for (int ks = 0; ks < 4; ++ks){     // k = 128 + ks*32 + lg*8 : msg features
      float4 a = m[2*ks], b = m[2*ks+1];
      uint4 w; w.x = pack2(a.x,a.y); w.y = pack2(a.z,a.w); w.z = pack2(b.x,b.y); w.w = pack2(b.z,b.w);
      B[4+ks] = *(bf16x8*)&w;
    }
    f32x4 acc[4];
    #pragma unroll
    for (int rt = 0; rt < 4; ++rt) acc[rt] = (f32x4){0.f,0.f,0.f,0.f};
    #pragma unroll
    for (int ks = 0; ks < 8; ++ks)
      #pragma unroll
      for (int rt = 0; rt < 4; ++rt)
        acc[rt] = __builtin_amdgcn_mfma_f32_16x16x32_bf16(Af[rt][ks], B[ks], acc[rt], 0, 0, 0);
    // D: col = lane&15 = edge, row = (lane>>4)*4+i = channel -> 4 contiguous ushorts
    #pragma unroll
    for (int rt = 0; rt < 4; ++rt){
      uint2 w = make_uint2(pack2(acc[rt][0], acc[rt][1]), pack2(acc[rt][2], acc[rt][3]));
      *(uint2*)(ep + (size_t)(e0 + lr) * 128 + half * 64 + rt * 16 + lg * 4) = w;
    }
  }
}

// ---------------- Sort: histogram -> 2-level exclusive scan -> placement --------------
__global__ void k_hist(const int* __restrict__ ei, int* __restrict__ deg){
  int e = blockIdx.x * 256 + threadIdx.x;
  if (e < EE) atomicAdd(&deg[ei[EE + e]], 1);
}

__global__ __launch_bounds__(256) void k_scan1(const int* __restrict__ deg,
                                               int* __restrict__ start,
                                               int* __restrict__ partial){
  __shared__ int sums[256];
  int b = blockIdx.x, tid = threadIdx.x;
  int base = b * 1024 + tid * 4;
  int d0 = (base + 0 < NN) ? deg[base + 0] : 0;
  int d1 = (base + 1 < NN) ? deg[base + 1] : 0;
  int d2 = (base + 2 < NN) ? deg[base + 2] : 0;
  int d3 = (base + 3 < NN) ? deg[base + 3] : 0;
  int s = d0 + d1 + d2 + d3;
  sums[tid] = s;
  __syncthreads();
  for (int off = 1; off < 256; off <<= 1){
    int v = (tid >= off) ? sums[tid - off] : 0;
    __syncthreads();
    sums[tid] += v;
    __syncthreads();
  }
  int excl = sums[tid] - s;
  if (base + 0 < NN) start[base + 0] = excl;
  if (base + 1 < NN) start[base + 1] = excl + d0;
  if (base + 2 < NN) start[base + 2] = excl + d0 + d1;
  if (base + 3 < NN) start[base + 3] = excl + d0 + d1 + d2;
  if (tid == 255) partial[b] = sums[255];
}

__global__ __launch_bounds__(128) void k_scan2(int* __restrict__ partial){
  __shared__ int s[128];
  int tid = threadIdx.x;
  int v = (tid < NB_SCAN) ? partial[tid] : 0;
  s[tid] = v;
  __syncthreads();
  for (int off = 1; off < 128; off <<= 1){
    int u = (tid >= off) ? s[tid - off] : 0;
    __syncthreads();
    s[tid] += u;
    __syncthreads();
  }
  if (tid < NB_SCAN) partial[tid] = s[tid] - v;  // exclusive
}

__global__ void k_scan3(int* __restrict__ start, const int* __restrict__ partial,
                        int* __restrict__ cursor){
  int i = blockIdx.x * 256 + threadIdx.x;
  if (i < NN){
    int v = start[i] + partial[i >> 10];
    start[i] = v;
    cursor[i] = v;
  }
  if (i == 0) start[NN] = EE;
}

// placement + rel fused (one pass over ei)
__global__ void k_place(const int* __restrict__ ei, const float* __restrict__ tt,
                        const float* __restrict__ lu, int* __restrict__ cursor,
                        uint2* __restrict__ sorted2, float* __restrict__ rel){
  int e = blockIdx.x * 256 + threadIdx.x;
  if (e < EE){
    int dst = ei[EE + e];
    int src = ei[e];
    rel[e] = tt[e] - lu[src];
    int pos = atomicAdd(&cursor[dst], 1);
    sorted2[pos] = make_uint2((uint)e, (uint)src);
  }
}

// ---------------- K3: per-node gather (shfl-batched indices, x4 MLP) ------------------
__global__ __launch_bounds__(256) void k_gather(
    const ushort* __restrict__ q_n, const ushort* __restrict__ kv,
    const ushort* __restrict__ ep, const int* __restrict__ start,
    const uint2* __restrict__ sorted2, float* __restrict__ out){
  int wave = (blockIdx.x * 256 + threadIdx.x) >> 6;
  if (wave >= NN) return;
  int n = wave;
  int l = threadIdx.x & 63;
  int c = l * 2;
  int s0 = start[n], s1 = start[n + 1];
  uint qq = *(const uint*)(q_n + (size_t)n * 128 + c);
  float q0 = bf2f(qq & 0xffff), q1 = bf2f(qq >> 16);
  float acc0 = 0.f, acc1 = 0.f, denom = 0.f;
  for (int base = s0; base < s1; base += 64){
    int chunk = s1 - base; if (chunk > 64) chunk = 64;
    uint2 myp = make_uint2(0u, 0u);
    if (l < chunk) myp = sorted2[base + l];
    int i = 0;
    for (; i + 4 <= chunk; i += 4){
      uint ia = __shfl(myp.x, i),     sa = __shfl(myp.y, i);
      uint ib = __shfl(myp.x, i + 1), sb = __shfl(myp.y, i + 1);
      uint ic = __shfl(myp.x, i + 2), sc = __shfl(myp.y, i + 2);
      uint id = __shfl(myp.x, i + 3), sd = __shfl(myp.y, i + 3);
      uint2 kv0 = *(const uint2*)(kv + (size_t)sa * 256 + c * 2);
      uint2 kv1 = *(const uint2*)(kv + (size_t)sb * 256 + c * 2);
      uint2 kv2 = *(const uint2*)(kv + (size_t)sc * 256 + c * 2);
      uint2 kv3 = *(const uint2*)(kv + (size_t)sd * 256 + c * 2);
      uint e0 = *(const uint*)(ep + (size_t)ia * 128 + c);
      uint e1 = *(const uint*)(ep + (size_t)ib * 128 + c);
      uint e2 = *(const uint*)(ep + (size_t)ic * 128 + c);
      uint e3 = *(const uint*)(ep + (size_t)id * 128 + c);
      float pa0 = bf2f(e0 & 0xffff), pa1 = bf2f(e0 >> 16);
      float pb0 = bf2f(e1 & 0xffff), pb1 = bf2f(e1 >> 16);
      float pc0 = bf2f(e2 & 0xffff), pc1 = bf2f(e2 >> 16);
      float pd0 = bf2f(e3 & 0xffff), pd1 = bf2f(e3 >> 16);
      float ka = q0 * (bf2f(kv0.x & 0xffff) + pa0) + q1 * (bf2f(kv0.x >> 16) + pa1);
      float kb = q0 * (bf2f(kv1.x & 0xffff) + pb0) + q1 * (bf2f(kv1.x >> 16) + pb1);
      float kc = q0 * (bf2f(kv2.x & 0xffff) + pc0) + q1 * (bf2f(kv2.x >> 16) + pc1);
      float kd = q0 * (bf2f(kv3.x & 0xffff) + pd0) + q1 * (bf2f(kv3.x >> 16) + pd1);
      #pragma unroll
      for (int off = 16; off > 0; off >>= 1){
        ka += __shfl_xor(ka, off);
        kb += __shfl_xor(kb, off);
        kc += __shfl_xor(kc, off);
        kd += __shfl_xor(kd, off);
      }
      float ea = __expf(ka * 0.125f), eb = __expf(kb * 0.125f);
      float ec = __expf(kc * 0.125f), ed = __expf(kd * 0.125f);
      denom += (ea + eb) + (ec + ed);
      acc0 += ea * (bf2f(kv0.y & 0xffff) + pa0) + eb * (bf2f(kv1.y & 0xffff) + pb0)
            + ec * (bf2f(kv2.y & 0xffff) + pc0) + ed * (bf2f(kv3.y & 0xffff) + pd0);
      acc1 += ea * (bf2f(kv0.y >> 16) + pa1) + eb * (bf2f(kv1.y >> 16) + pb1)
            + ec * (bf2f(kv2.y >> 16) + pc1) + ed * (bf2f(kv3.y >> 16) + pd1);
    }
    for (; i + 2 <= chunk; i += 2){
      uint ia = __shfl(myp.x, i),     sa = __shfl(myp.y, i);
      uint ib = __shfl(myp.x, i + 1), sb = __shfl(myp.y, i + 1);
      uint2 kv0 = *(const uint2*)(kv + (size_t)sa * 256 + c * 2);
      uint2 kv1 = *(const uint2*)(kv + (size_t)sb * 256 + c * 2);
      uint e0 = *(const uint*)(ep + (size_t)ia * 128 + c);
      uint e1 = *(const uint*)(ep + (size_t)ib * 128 + c);
      float pa0 = bf2f(e0 & 0xffff), pa1 = bf2f(e0 >> 16);
      float pb0 = bf2f(e1 & 0xffff), pb1 = bf2f(e1 >> 16);
      float ka = q0 * (bf2f(kv0.x & 0xffff) + pa0) + q1 * (bf2f(kv0.x >> 16) + pa1);
      float kb = q0 * (bf2f(kv1.x & 0xffff) + pb0) + q1 * (bf2f(kv1.x >> 16) + pb1);
      #pragma unroll
      for (int off = 16; off > 0; off >>= 1){
        ka += __shfl_xor(ka, off);
        kb += __shfl_xor(kb, off);
      }
      float ea = __expf(ka * 0.125f), eb = __expf(kb * 0.125f);
      denom += ea + eb;
      acc0 += ea * (bf2f(kv0.y & 0xffff) + pa0) + eb * (bf2f(kv1.y & 0xffff) + pb0);
      acc1 += ea * (bf2f(kv0.y >> 16) + pa1) + eb * (bf2f(kv1.y >> 16) + pb1);
    }
    if (i < chunk){
      uint ia = __shfl(myp.x, i), sa = __shfl(myp.y, i);
      uint2 kv0 = *(const uint2*)(kv + (size_t)sa * 256 + c * 2);
      uint e0 = *(const uint*)(ep + (size_t)ia * 128 + c);
      float pa0 = bf2f(e0 & 0xffff), pa1 = bf2f(e0 >> 16);
      float ka = q0 * (bf2f(kv0.x & 0xffff) + pa0) + q1 * (bf2f(kv0.x >> 16) + pa1);
      #pragma unroll
      for (int off = 16; off > 0; off >>= 1) ka += __shfl_xor(ka, off);
      float ea = __expf(ka * 0.125f);
      denom += ea;
      acc0 += ea * (bf2f(kv0.y & 0xffff) + pa0);
      acc1 += ea * (bf2f(kv0.y >> 16) + pa1);
    }
  }
  float inv = 1.0f / (denom + 1e-16f);
  size_t o = (size_t)n * 128 + c;
  out[o]     += acc0 * inv;
  out[o + 1] += acc1 * inv;
}

extern "C" void kernel_launch(void* const* d_in, const int* in_sizes, int n_in,
                              void* d_out, int out_size, void* d_ws, size_t ws_size,
                              hipStream_t stream) {
  const float* x   = (const float*)d_in[0];
  const float* lu  = (const float*)d_in[1];
  const float* t   = (const float*)d_in[2];
  const float* msg = (const float*)d_in[3];
  const float* tw  = (const float*)d_in[4];
  const float* tb  = (const float*)d_in[5];
  const float* Wq  = (const float*)d_in[6];
  const float* bq  = (const float*)d_in[7];
  const float* Wk  = (const float*)d_in[8];
  const float* bk  = (const float*)d_in[9];
  const float* Wv  = (const float*)d_in[10];
  const float* bv  = (const float*)d_in[11];
  const float* We  = (const float*)d_in[12];
  const float* Wsk = (const float*)d_in[13];
  const float* bsk = (const float*)d_in[14];
  const int*   ei  = (const int*)d_in[15];
  float* out = (float*)d_out;

  char* w = (char*)d_ws;
  size_t off = 0;
  auto nxt = [&](size_t b){ size_t r = off; off += (b + 255) & ~(size_t)255; return r; };
  ushort* q_n   = (ushort*)(w + nxt((size_t)NN * 128 * 2));
  ushort* kv    = (ushort*)(w + nxt((size_t)NN * 256 * 2));
  ushort* epj   = (ushort*)(w + nxt((size_t)EE * 128 * 2));
  ushort* W4t   = (ushort*)(w + nxt((size_t)512 * 128 * 2));
  ushort* Wet   = (ushort*)(w + nxt((size_t)128 * 256 * 2));
  int* deg      = (int*)(w + nxt((size_t)NN * 4));
  int* start    = (int*)(w + nxt((size_t)(NN + 1) * 4));
  int* cursor   = (int*)(w + nxt((size_t)NN * 4));
  int* partial  = (int*)(w + nxt((size_t)(NB_SCAN + 1) * 4));
  uint2* sorted2 = (uint2*)(w + nxt((size_t)EE * 8));
  float* rel    = (float*)(w + nxt((size_t)EE * 4));

  k_prep<<<(NN + 255) / 256, 256, 0, stream>>>(Wq, Wk, Wv, Wsk, We, W4t, Wet, deg);
  k_node<<<(NN + 63) / 64, 256, 0, stream>>>(x, W4t, bq, bk, bv, bsk, q_n, kv, out);
  k_hist<<<(EE + 255) / 256, 256, 0, stream>>>(ei, deg);
  k_scan1<<<NB_SCAN, 256, 0, stream>>>(deg, start, partial);
  k_scan2<<<1, 128, 0, stream>>>(partial);
  k_scan3<<<(NN + 255) / 256, 256, 0, stream>>>(start, partial, cursor);
  k_place<<<(EE + 255) / 256, 256, 0, stream>>>(ei, t, lu, cursor, sorted2, rel);
  k_edge3<<<G_E3, 256, 0, stream>>>(rel, msg, tw, tb, Wet, epj);
  k_gather<<<(NN * 64 + 255) / 256, 256, 0, stream>>>(q_n, kv, epj, start, sorted2, out);
}